// Round 8
// baseline (150.195 us; speedup 1.0000x reference)
//
#include <hip/hip_runtime.h>
#include <stdint.h>

// -------------------------------------------------------------------------
// UpperBandEntropyLoss16 via MFMA (R7-verified math) + R8 strip pipelining.
//
// R7 -> R8: three different compute pipelines (scalar, coalesced-scalar,
// MFMA) all timed identical => controllable time is per-wave fixed cost +
// exposed HBM latency + dispatch, not pipe throughput. Now 1536 workgroups;
// each wave processes 4 strips (16x64) sequentially, prefetching the next
// strip's 4x float4 loads right after packing the current one (loads get
// ~1800 cyc of cover). 4x fewer waves/dispatches/partials.
// -------------------------------------------------------------------------

typedef float f32x4 __attribute__((ext_vector_type(4)));
typedef short bf16x8 __attribute__((ext_vector_type(8)));

constexpr double kPi = 3.14159265358979323846;

constexpr double ccos(double x) {
    while (x > kPi) x -= 2.0 * kPi;
    while (x < -kPi) x += 2.0 * kPi;
    double x2 = x * x;
    double term = 1.0, sum = 1.0;
    for (int k = 1; k <= 24; ++k) {
        term *= -x2 / (double)((2 * k - 1) * (2 * k));
        sum += term;
    }
    return sum;
}

// HARM[i][f] = cos((2i+1) * f*pi/32), f32-rounded like numpy's build.
constexpr float fharm(int i, int f) {
    float colf = (float)((double)f * kPi) / 32.0f;
    float arg = (2.0f * (float)i + 1.0f) * colf;
    return (float)ccos((double)arg);
}

constexpr uint16_t f2bf(float f) {
    unsigned u = __builtin_bit_cast(unsigned, f);
    return (uint16_t)((u + 0x7fffu + ((u >> 16) & 1u)) >> 16);
}

// MFMA 16x16x32 fragment layouts (gfx950, HW-verified in guide):
//   A[m = lane&15][k = (lane>>4)*8 + j]   (8 bf16 / lane)
//   B[k = (lane>>4)*8 + j][n = lane&15]
//   C/D: col = lane&15, row = (lane>>4)*4 + reg
struct FragTables {
    alignas(16) uint32_t blo[64][4];  // B = [G2n ; 0]   (selects K lower half)
    alignas(16) uint32_t bhi[64][4];  // B = [0 ; G2n]   (selects K upper half)
    alignas(16) uint32_t a2[64][4];   // A = [Gu | 0],  Gu[u][i]=H[i][u]*n_u*S
    constexpr FragTables() : blo{}, bhi{}, a2{} {
        for (int l = 0; l < 64; ++l) {
            const int n = l & 15;  // B: freq col v ; A2: freq row u
            const int q = l >> 4;
            uint16_t slo[8] = {}, shi[8] = {}, sa[8] = {};
            for (int s = 0; s < 8; ++s) {
                const int k = 8 * q + s;
                if (k < 16) {
                    float g = fharm(k, n) *
                              ((n == 0) ? 0.70710678118654752440f : 1.0f);
                    slo[s] = f2bf(g);
                    sa[s] = f2bf(g * 0.17677669529663688110f);  // 1/sqrt(32)
                } else {
                    float g = fharm(k - 16, n) *
                              ((n == 0) ? 0.70710678118654752440f : 1.0f);
                    shi[s] = f2bf(g);
                }
            }
            for (int d = 0; d < 4; ++d) {
                blo[l][d] = (uint32_t)slo[2 * d] | ((uint32_t)slo[2 * d + 1] << 16);
                bhi[l][d] = (uint32_t)shi[2 * d] | ((uint32_t)shi[2 * d + 1] << 16);
                a2[l][d] = (uint32_t)sa[2 * d] | ((uint32_t)sa[2 * d + 1] << 16);
            }
        }
    }
};
__constant__ FragTables kF{};

#define NWG 1536
#define NPART (NWG * 4)

// Intra-wave phase boundary: HW lockstep + in-order DS pipe give ordering;
// the waitcnt+clobber stops the compiler from reordering across it.
#define WAVE_LDS_FENCE() asm volatile("s_waitcnt lgkmcnt(0)" ::: "memory")

// bf16 round-to-nearest-even pack, pure integer (matches _rn for non-NaN).
__device__ __forceinline__ uint32_t bfr(float f) {
    uint32_t u = __float_as_uint(f);
    return (u + 0x7fffu + ((u >> 16) & 1u)) >> 16;
}
__device__ __forceinline__ uint32_t pk2(float a, float b) {
    return bfr(a) | (bfr(b) << 16);
}

__global__ __launch_bounds__(256, 4) void dct_entropy_kernel(
    const float* __restrict__ x, float* __restrict__ partials) {
    // per-wave region: 1344 dwords (W_cm 768 + Ccm 1296 overlaid, + slack)
    __shared__ float smem[4 * 1344];

    const int t = threadIdx.x;
    const int wave = t >> 6;
    const int lane = t & 63;
    const int l15 = lane & 15;  // A-row i / D-col v / entropy col
    const int q = lane >> 4;
    float* R = smem + wave * 1344;
    uint32_t* Rw = (uint32_t*)R;

    const int g = blockIdx.x;

    // Strip s (0..24575) = 16 rows x 64 cols: bc = s>>10, br = (s>>4)&63,
    // column strip cs = s&15. Wave handles strips s = g*16 + it*4 + wave.
    const int s0 = (g << 4) + wave;

    // lane's fixed offset within a strip: row l15, cols 8q.. (+32 for c=1)
    const size_t lane_off = (size_t)l15 * 1024 + 8 * q;

    auto strip_ptr = [&](int it) -> const float* {
        const int s = s0 + (it << 2);
        const int bc = s >> 10;
        const int br = (s >> 4) & 63;
        const int cs = s & 15;
        return x + ((size_t)bc << 20) + ((size_t)br << 14) + (cs << 6) +
               lane_off;
    };

    const bf16x8 fBlo = __builtin_bit_cast(bf16x8, *(const uint4*)kF.blo[lane]);
    const bf16x8 fBhi = __builtin_bit_cast(bf16x8, *(const uint4*)kF.bhi[lane]);
    const bf16x8 fA2 = __builtin_bit_cast(bf16x8, *(const uint4*)kF.a2[lane]);
    const f32x4 z = {0.0f, 0.0f, 0.0f, 0.0f};

    // ---- prologue: loads for strip 0 ----
    const float* rp = strip_ptr(0);
    float4 lo0 = *(const float4*)(rp);
    float4 hi0 = *(const float4*)(rp + 4);
    float4 lo1 = *(const float4*)(rp + 32);
    float4 hi1 = *(const float4*)(rp + 36);

    float etot = 0.0f;

#pragma unroll
    for (int it = 0; it < 4; ++it) {
        // pack current strip's A-frags
        uint4 ua0 = {pk2(lo0.x, lo0.y), pk2(lo0.z, lo0.w),
                     pk2(hi0.x, hi0.y), pk2(hi0.z, hi0.w)};
        uint4 ua1 = {pk2(lo1.x, lo1.y), pk2(lo1.z, lo1.w),
                     pk2(hi1.x, hi1.y), pk2(hi1.z, hi1.w)};
        const bf16x8 fA0 = __builtin_bit_cast(bf16x8, ua0);
        const bf16x8 fA1 = __builtin_bit_cast(bf16x8, ua1);

        // prefetch next strip (covered by this strip's whole pipeline body)
        if (it < 3) {
            const float* np = strip_ptr(it + 1);
            lo0 = *(const float4*)(np);
            hi0 = *(const float4*)(np + 4);
            lo1 = *(const float4*)(np + 32);
            hi1 = *(const float4*)(np + 36);
        }

        // ---- stage A: W_b = X_b * G2n (4 MFMAs; B const selects K half) --
        f32x4 W0 = __builtin_amdgcn_mfma_f32_16x16x32_bf16(fA0, fBlo, z, 0, 0, 0);
        f32x4 W1 = __builtin_amdgcn_mfma_f32_16x16x32_bf16(fA0, fBhi, z, 0, 0, 0);
        f32x4 W2 = __builtin_amdgcn_mfma_f32_16x16x32_bf16(fA1, fBlo, z, 0, 0, 0);
        f32x4 W3 = __builtin_amdgcn_mfma_f32_16x16x32_bf16(fA1, fBhi, z, 0, 0, 0);

        // previous iteration's entropy ds_reads are complete (in-order DS
        // pipe); clobber stops compiler reordering across region reuse.
        WAVE_LDS_FENCE();

        // ---- transpose: D-layout -> B-layout via LDS ----
        // W_cm[block][v][i] bf16, row pitch 12 dwords; dwords 8..11 slack.
        {
            const int wi = 12 * l15 + 2 * q;
            *(uint2*)(&Rw[wi]) = make_uint2(pk2(W0.x, W0.y), pk2(W0.z, W0.w));
            *(uint2*)(&Rw[192 + wi]) =
                make_uint2(pk2(W1.x, W1.y), pk2(W1.z, W1.w));
            *(uint2*)(&Rw[384 + wi]) =
                make_uint2(pk2(W2.x, W2.y), pk2(W2.z, W2.w));
            *(uint2*)(&Rw[576 + wi]) =
                make_uint2(pk2(W3.x, W3.y), pk2(W3.z, W3.w));
        }
        WAVE_LDS_FENCE();

        // B-frag read; k>=16 lanes re-read k<16 data (annihilated by fA2's
        // exact zero padding; avoids 0*NaN from unwritten slack — R6 fix).
        bf16x8 fW[4];
        {
            const int ri = 12 * l15 + 4 * (q & 1);
#pragma unroll
            for (int b = 0; b < 4; ++b)
                fW[b] = __builtin_bit_cast(bf16x8,
                                           *(const uint4*)(&Rw[192 * b + ri]));
        }
        WAVE_LDS_FENCE();  // B reads ordered before Ccm overlay-writes

        // ---- stage B: C_b = Gu * W_b; store column-major fp32 ----
        // Ccm[block][v][u] pitch 20 dwords, block base 324 dwords.
        {
#pragma unroll
            for (int b = 0; b < 4; ++b) {
                f32x4 C = __builtin_amdgcn_mfma_f32_16x16x32_bf16(fA2, fW[b],
                                                                  z, 0, 0, 0);
                *(f32x4*)(&R[324 * b + 20 * l15 + 4 * q]) = C;
            }
        }
        WAVE_LDS_FENCE();

        // ---- entropy (R4-verified): lane = (block q, column v=l15) ----
        {
            const float* C = &R[324 * q + 20 * l15];
            float c[16];
#pragma unroll
            for (int k = 0; k < 4; ++k) {
                float4 f = *(const float4*)(C + 4 * k);
                c[4 * k + 0] = f.x;
                c[4 * k + 1] = f.y;
                c[4 * k + 2] = f.z;
                c[4 * k + 3] = f.w;
            }
            const int v = l15;
            const int u_min = (v > 7) ? (16 - v) : (15 - v);

            float s = 0.0f;
#pragma unroll
            for (int u = 0; u < 16; ++u) s += (u >= u_min) ? c[u] : 0.0f;
#pragma unroll
            for (int m = 1; m <= 8; m <<= 1) s += __shfl_xor(s, m);
            const float mean = s * (1.0f / 128.0f);

            float a[16];
            float sq = 0.0f;
#pragma unroll
            for (int u = 0; u < 16; ++u) {
                float au = (c[u] < mean) ? 1e-12f : (fabsf(c[u]) + 1e-12f);
                a[u] = (u >= u_min) ? au : 0.0f;
                sq = fmaf(a[u], a[u], sq);
            }
#pragma unroll
            for (int m = 1; m <= 8; m <<= 1) sq += __shfl_xor(sq, m);
            const float inv = 1.0f / fmaxf(sqrtf(sq), 1e-12f);

            float e = 0.0f;
#pragma unroll
            for (int u = 0; u < 16; ++u) {
                float p = a[u] * inv;
                float term = p * __log2f(p);
                e += (u >= u_min) ? term : 0.0f;
            }
            // reduce within block (xor 1..8), then across the 4 blocks
#pragma unroll
            for (int m = 1; m <= 32; m <<= 1) e += __shfl_xor(e, m);
            etot += e;  // full-wave sum lives in every lane
        }
    }

    if (lane == 0) partials[(g << 2) + wave] = etot;
}

__global__ __launch_bounds__(256) void reduce_partials(
    const float* __restrict__ partials, float* __restrict__ out) {
    __shared__ float s[4];
    float v = 0.0f;
    const float4* p4 = (const float4*)partials;
#pragma unroll
    for (int k = 0; k < NPART / 4 / 256; ++k) {
        float4 f = p4[threadIdx.x + 256 * k];
        v += (f.x + f.y) + (f.z + f.w);
    }
#pragma unroll
    for (int m = 1; m <= 32; m <<= 1) v += __shfl_xor(v, m);
    if ((threadIdx.x & 63) == 0) s[threadIdx.x >> 6] = v;
    __syncthreads();
    if (threadIdx.x == 0) {
        float tot = (s[0] + s[1]) + (s[2] + s[3]);
        out[0] = tot * (-1.0f / 98304.0f);
    }
}

extern "C" void kernel_launch(void* const* d_in, const int* in_sizes, int n_in,
                              void* d_out, int out_size, void* d_ws,
                              size_t ws_size, hipStream_t stream) {
    const float* x = (const float*)d_in[0];
    float* out = (float*)d_out;
    float* ws = (float*)d_ws;  // 6144 per-wave partials
    dct_entropy_kernel<<<NWG, 256, 0, stream>>>(x, ws);
    reduce_partials<<<1, 256, 0, stream>>>(ws, out);
}

// Round 9
// 144.024 us; speedup vs baseline: 1.0428x; 1.0428x over previous
//
#include <hip/hip_runtime.h>
#include <stdint.h>

// -------------------------------------------------------------------------
// UpperBandEntropyLoss16 via MFMA.
//
// R8 -> R9: R8's 4x strip serialization regressed (fewer resident waves,
// serial critical path) -> reverted to R7's 6144-wg grid. R7's residual
// bottleneck: VALU issue in the epilogue (~50 instr RNE packing + ~200
// instr entropy, half wasted on masked-out band slots). R9: (1) truncating
// bf16 pack (2 VALU/pair, error still ~2^-8 rel, absmax margin is ~10x);
// (2) dense band remap: column p pairs with column 15-p (p+1 + 15-p = 16
// slots) -> each lane reads exactly 8 in-band coeffs via 8 ds_read_b32
// with closed-form addresses; entropy has no masking at all.
// -------------------------------------------------------------------------

typedef float f32x4 __attribute__((ext_vector_type(4)));
typedef short bf16x8 __attribute__((ext_vector_type(8)));

constexpr double kPi = 3.14159265358979323846;

constexpr double ccos(double x) {
    while (x > kPi) x -= 2.0 * kPi;
    while (x < -kPi) x += 2.0 * kPi;
    double x2 = x * x;
    double term = 1.0, sum = 1.0;
    for (int k = 1; k <= 24; ++k) {
        term *= -x2 / (double)((2 * k - 1) * (2 * k));
        sum += term;
    }
    return sum;
}

// HARM[i][f] = cos((2i+1) * f*pi/32), f32-rounded like numpy's build.
constexpr float fharm(int i, int f) {
    float colf = (float)((double)f * kPi) / 32.0f;
    float arg = (2.0f * (float)i + 1.0f) * colf;
    return (float)ccos((double)arg);
}

constexpr uint16_t f2bf(float f) {
    unsigned u = __builtin_bit_cast(unsigned, f);
    return (uint16_t)((u + 0x7fffu + ((u >> 16) & 1u)) >> 16);
}

// MFMA 16x16x32 fragment layouts (gfx950, HW-verified in guide):
//   A[m = lane&15][k = (lane>>4)*8 + j]   (8 bf16 / lane)
//   B[k = (lane>>4)*8 + j][n = lane&15]
//   C/D: col = lane&15, row = (lane>>4)*4 + reg
struct FragTables {
    alignas(16) uint32_t blo[64][4];  // B = [G2n ; 0]   (selects K lower half)
    alignas(16) uint32_t bhi[64][4];  // B = [0 ; G2n]   (selects K upper half)
    alignas(16) uint32_t a2[64][4];   // A = [Gu | 0],  Gu[u][i]=H[i][u]*n_u*S
    constexpr FragTables() : blo{}, bhi{}, a2{} {
        for (int l = 0; l < 64; ++l) {
            const int n = l & 15;  // B: freq col v ; A2: freq row u
            const int q = l >> 4;
            uint16_t slo[8] = {}, shi[8] = {}, sa[8] = {};
            for (int s = 0; s < 8; ++s) {
                const int k = 8 * q + s;
                if (k < 16) {
                    float g = fharm(k, n) *
                              ((n == 0) ? 0.70710678118654752440f : 1.0f);
                    slo[s] = f2bf(g);
                    sa[s] = f2bf(g * 0.17677669529663688110f);  // 1/sqrt(32)
                } else {
                    float g = fharm(k - 16, n) *
                              ((n == 0) ? 0.70710678118654752440f : 1.0f);
                    shi[s] = f2bf(g);
                }
            }
            for (int d = 0; d < 4; ++d) {
                blo[l][d] = (uint32_t)slo[2 * d] | ((uint32_t)slo[2 * d + 1] << 16);
                bhi[l][d] = (uint32_t)shi[2 * d] | ((uint32_t)shi[2 * d + 1] << 16);
                a2[l][d] = (uint32_t)sa[2 * d] | ((uint32_t)sa[2 * d + 1] << 16);
            }
        }
    }
};
__constant__ FragTables kF{};

#define NWG 6144
#define NPART (NWG * 4)

// Intra-wave phase boundary: HW lockstep + in-order DS pipe give ordering;
// the waitcnt+clobber stops the compiler from reordering across it.
#define WAVE_LDS_FENCE() asm volatile("s_waitcnt lgkmcnt(0)" ::: "memory")

// Truncating bf16x2 pack: low half from a's high 16 bits, high half from b.
// 2 VALU ops (lshr + and_or); truncation error <= 2^-8 rel, fine here.
__device__ __forceinline__ uint32_t pk2(float a, float b) {
    return (__float_as_uint(a) >> 16) | (__float_as_uint(b) & 0xffff0000u);
}

__global__ __launch_bounds__(256, 4) void dct_entropy_kernel(
    const float* __restrict__ x, float* __restrict__ partials) {
    // per-wave region: 1344 dwords (W_cm 768 + Ccm 1296 overlaid, + slack)
    __shared__ float smem[4 * 1344];

    const int t = threadIdx.x;
    const int wave = t >> 6;
    const int lane = t & 63;
    const int l15 = lane & 15;  // A-row i / D-col v / entropy slot group
    const int q = lane >> 4;
    float* R = smem + wave * 1344;
    uint32_t* Rw = (uint32_t*)R;

    const int g = blockIdx.x;
    const int bc = g >> 8;         // 0..23 (b*c)
    const int br = (g >> 2) & 63;  // block row
    const int cg = g & 3;          // 256-col group
    const float* gbase =
        x + ((size_t)bc << 20) + ((size_t)br << 14) + (cg << 8) + (wave << 6);

    // ---- A-frags: lane reads X[i=l15][32c + 8q + 0..7], c=0,1 ----
    const float* rp = gbase + (size_t)l15 * 1024 + 8 * q;
    float4 lo0 = *(const float4*)(rp);
    float4 hi0 = *(const float4*)(rp + 4);
    float4 lo1 = *(const float4*)(rp + 32);
    float4 hi1 = *(const float4*)(rp + 36);

    const bf16x8 fBlo = __builtin_bit_cast(bf16x8, *(const uint4*)kF.blo[lane]);
    const bf16x8 fBhi = __builtin_bit_cast(bf16x8, *(const uint4*)kF.bhi[lane]);
    const bf16x8 fA2 = __builtin_bit_cast(bf16x8, *(const uint4*)kF.a2[lane]);

    uint4 ua0 = {pk2(lo0.x, lo0.y), pk2(lo0.z, lo0.w),
                 pk2(hi0.x, hi0.y), pk2(hi0.z, hi0.w)};
    uint4 ua1 = {pk2(lo1.x, lo1.y), pk2(lo1.z, lo1.w),
                 pk2(hi1.x, hi1.y), pk2(hi1.z, hi1.w)};
    const bf16x8 fA0 = __builtin_bit_cast(bf16x8, ua0);
    const bf16x8 fA1 = __builtin_bit_cast(bf16x8, ua1);

    // ---- stage A: W_b = X_b * G2n  (4 MFMAs; B const selects K half) ----
    const f32x4 z = {0.0f, 0.0f, 0.0f, 0.0f};
    f32x4 W0 = __builtin_amdgcn_mfma_f32_16x16x32_bf16(fA0, fBlo, z, 0, 0, 0);
    f32x4 W1 = __builtin_amdgcn_mfma_f32_16x16x32_bf16(fA0, fBhi, z, 0, 0, 0);
    f32x4 W2 = __builtin_amdgcn_mfma_f32_16x16x32_bf16(fA1, fBlo, z, 0, 0, 0);
    f32x4 W3 = __builtin_amdgcn_mfma_f32_16x16x32_bf16(fA1, fBhi, z, 0, 0, 0);

    // ---- transpose: D-layout -> B-layout via LDS (b64 writes) ----
    // W_cm[block][v][i] bf16, row pitch 12 dwords; dwords 8..11 slack.
    {
        const int wi = 12 * l15 + 2 * q;
        *(uint2*)(&Rw[wi]) = make_uint2(pk2(W0.x, W0.y), pk2(W0.z, W0.w));
        *(uint2*)(&Rw[192 + wi]) = make_uint2(pk2(W1.x, W1.y), pk2(W1.z, W1.w));
        *(uint2*)(&Rw[384 + wi]) = make_uint2(pk2(W2.x, W2.y), pk2(W2.z, W2.w));
        *(uint2*)(&Rw[576 + wi]) = make_uint2(pk2(W3.x, W3.y), pk2(W3.z, W3.w));
    }
    WAVE_LDS_FENCE();

    // B-frag read; k>=16 lanes re-read k<16 data (annihilated by fA2's
    // exact zero padding; avoids 0*NaN from unwritten slack — R6 fix).
    bf16x8 fW[4];
    {
        const int ri = 12 * l15 + 4 * (q & 1);
#pragma unroll
        for (int b = 0; b < 4; ++b)
            fW[b] = __builtin_bit_cast(bf16x8, *(const uint4*)(&Rw[192 * b + ri]));
    }
    WAVE_LDS_FENCE();  // all B reads ordered before Ccm overlay-writes

    // ---- stage B: C_b = Gu * W_b; store column-major fp32 ----
    // Ccm[block][v][u] pitch 20 dwords, block base 324 dwords.
    {
#pragma unroll
        for (int b = 0; b < 4; ++b) {
            f32x4 C = __builtin_amdgcn_mfma_f32_16x16x32_bf16(fA2, fW[b], z, 0, 0, 0);
            *(f32x4*)(&R[324 * b + 20 * l15 + 4 * q]) = C;
        }
    }
    WAVE_LDS_FENCE();

    // ---- entropy: dense band remap, 8 in-band coeffs per lane ----
    // Pair p = l15>>1 couples column v1=p (u_min=15-p, count p+1) with
    // column v2=15-p (u_min=p+1, count 15-p): exactly 16 slots. Half h
    // = l15&1 takes slots s=8h..8h+7. Address (dwords into block region):
    //   s <= p : 19p + 15 + s       (run in column p)
    //   else   : 300 - 20p + s      (run in column 15-p)
    {
        const int p = l15 >> 1;
        const int h = l15 & 1;
        const float* Cb = &R[324 * q];
        float c[8];
#pragma unroll
        for (int j = 0; j < 8; ++j) {
            const int s = 8 * h + j;
            const int off = (s <= p) ? (19 * p + 15 + s) : (300 - 20 * p + s);
            c[j] = Cb[off];
        }

        float s = ((c[0] + c[1]) + (c[2] + c[3])) +
                  ((c[4] + c[5]) + (c[6] + c[7]));
#pragma unroll
        for (int m = 1; m <= 8; m <<= 1) s += __shfl_xor(s, m);
        const float mean = s * (1.0f / 128.0f);

        float a[8];
        float sq = 0.0f;
#pragma unroll
        for (int j = 0; j < 8; ++j) {
            a[j] = (c[j] < mean) ? 1e-12f : (fabsf(c[j]) + 1e-12f);
            sq = fmaf(a[j], a[j], sq);
        }
#pragma unroll
        for (int m = 1; m <= 8; m <<= 1) sq += __shfl_xor(sq, m);
        const float inv = 1.0f / fmaxf(sqrtf(sq), 1e-12f);

        float e = 0.0f;
#pragma unroll
        for (int j = 0; j < 8; ++j) {
            float pj = a[j] * inv;
            e = fmaf(pj, __log2f(pj), e);
        }
        // reduce within block (xor 1..8), then across the wave's 4 blocks
#pragma unroll
        for (int m = 1; m <= 32; m <<= 1) e += __shfl_xor(e, m);
        if (lane == 0) partials[(g << 2) + wave] = e;
    }
}

__global__ __launch_bounds__(1024) void reduce_partials(
    const float* __restrict__ partials, float* __restrict__ out) {
    __shared__ float s[16];
    float v = 0.0f;
    const float4* p4 = (const float4*)partials;
    for (int i = threadIdx.x; i < NPART / 4; i += 1024) {
        float4 f = p4[i];
        v += (f.x + f.y) + (f.z + f.w);
    }
#pragma unroll
    for (int m = 1; m <= 32; m <<= 1) v += __shfl_xor(v, m);
    if ((threadIdx.x & 63) == 0) s[threadIdx.x >> 6] = v;
    __syncthreads();
    if (threadIdx.x < 16) {
        float tot = s[threadIdx.x];
#pragma unroll
        for (int m = 1; m <= 8; m <<= 1) tot += __shfl_xor(tot, m);
        if (threadIdx.x == 0) out[0] = tot * (-1.0f / 98304.0f);
    }
}

extern "C" void kernel_launch(void* const* d_in, const int* in_sizes, int n_in,
                              void* d_out, int out_size, void* d_ws,
                              size_t ws_size, hipStream_t stream) {
    const float* x = (const float*)d_in[0];
    float* out = (float*)d_out;
    float* ws = (float*)d_ws;  // 24576 per-wave partials
    dct_entropy_kernel<<<NWG, 256, 0, stream>>>(x, ws);
    reduce_partials<<<1, 1024, 0, stream>>>(ws, out);
}